// Round 13
// baseline (357.531 us; speedup 1.0000x reference)
//
#include <hip/hip_runtime.h>
#include <hip/hip_fp16.h>
#include <math.h>

// Problem constants
#define B_     4
#define CIN    128
#define LEN    2048
#define DMODEL 256
#define DSTATE 16
#define NHEADS 256
#define DINNER 768
#define CONVDIM 800      // DINNER + 2*DSTATE
#define DINPROJ 1824     // 2*DINNER + 2*DSTATE + NHEADS
#define EPS_   1e-5f
#define BAND   64        // rows per k_y block
#define NBAND  32        // LEN / BAND

typedef _Float16 f16x8 __attribute__((ext_vector_type(8)));
typedef _Float16 f16x4 __attribute__((ext_vector_type(4)));
typedef float    f32x4 __attribute__((ext_vector_type(4)));

__device__ __forceinline__ float silu_(float x){ return x / (1.0f + __expf(-x)); }
__device__ __forceinline__ float softplus_(float x){
    return x > 0.f ? x + log1pf(__expf(-x)) : log1pf(__expf(x));
}

// async global->LDS, 16B per lane; LDS dest = wave-uniform base + lane*16
__device__ __forceinline__ void gl2lds16(const _Float16* g, _Float16* l){
    __builtin_amdgcn_global_load_lds(
        (const __attribute__((address_space(1))) void*)g,
        (__attribute__((address_space(3))) void*)l, 16, 0, 0);
}

// ---------------------------------------------------------------------------
// fp32 -> fp16 convert for the three weight tensors, one launch
// ---------------------------------------------------------------------------
__global__ __launch_bounds__(256) void k_f2h3(const float* __restrict__ a0,
                                              _Float16* __restrict__ o0, int n0,
                                              const float* __restrict__ a1,
                                              _Float16* __restrict__ o1, int n1,
                                              const float* __restrict__ a2,
                                              _Float16* __restrict__ o2, int n2){
    int stride = gridDim.x * 256;
    for (int i = blockIdx.x * 256 + threadIdx.x; i < n0; i += stride)
        o0[i] = (_Float16)a0[i];
    for (int i = blockIdx.x * 256 + threadIdx.x; i < n1; i += stride)
        o1[i] = (_Float16)a1[i];
    for (int i = blockIdx.x * 256 + threadIdx.x; i < n2; i += stride)
        o2[i] = (_Float16)a2[i];
}

// ---------------------------------------------------------------------------
// im2col for the conv projection: xcol[(b,l)][(ci,k)] = x[b,ci,l-1+k], fp16.
// ---------------------------------------------------------------------------
__global__ __launch_bounds__(256) void k_im2col(const float* __restrict__ x,
                                                _Float16* __restrict__ xcol){
    __shared__ float xs[CIN][68];      // 67 used
    int blk = blockIdx.x;              // 0..127
    int b  = blk >> 5;
    int l0 = (blk & 31) << 6;          // *64
    const float* xb = x + (size_t)b * CIN * LEN;
    for (int idx = threadIdx.x; idx < CIN * 67; idx += 256){
        int ci = idx / 67, j = idx % 67;
        int gl = l0 - 1 + j;
        xs[ci][j] = (gl >= 0 && gl < LEN) ? xb[ci * LEN + gl] : 0.f;
    }
    __syncthreads();
    #pragma unroll
    for (int v = 0; v < 16; v++){
        int id = v * 256 + threadIdx.x;   // 0..4095
        int rl = id >> 6, c = id & 63;    // row-in-tile, 16B chunk
        f16x8 pk;
        #pragma unroll
        for (int e = 0; e < 8; e++){
            int ci = c * 2 + (e >> 2), k = e & 3;
            pk[e] = (_Float16)xs[ci][rl + k];
        }
        *(f16x8*)&xcol[((size_t)(b * LEN + l0 + rl)) * 512 + c * 8] = pk;
    }
}

// ---------------------------------------------------------------------------
// Shared MFMA GEMM: C[M][N] = A[M][K] . Bw[N][K]^T, f16 inputs, fp32 acc.
// BK=64, XOR-swizzled fragment reads (linear gl2lds dest + inverse-swizzled
// global source + same swizzle on read). MT = M-tile rows:
//   MT=128 (EPI 1): proven 59us path, unchanged.
//   MT=64  (EPI 0/2): half tile -> 2x blocks -> full 256-CU fill for the
//   grids that were only 128 blocks (gemm0/gemm2); acc[2][4]=32 VGPR, 24.5KB
//   LDS -> 6 blocks/CU, overlapping the per-block vmcnt(0) drains.
// Epilogues stage through LDS (EP aliases As/Bs) -> 16B coalesced stores.
// ---------------------------------------------------------------------------
template<int K, int EPI, int MT>
__global__ __launch_bounds__(256) void k_gemm(const _Float16* __restrict__ A,
                                              const _Float16* __restrict__ Bw,
                                              const float* __restrict__ dt_bias,
                                              _Float16* __restrict__ o_u,
                                              _Float16* __restrict__ o_z,
                                              _Float16* __restrict__ o_xbc,
                                              _Float16* __restrict__ o_dt,
                                              float* __restrict__ o_f){
    __shared__ __align__(16) char smem[(MT + 128) * 64 * 2];
    _Float16* As = (_Float16*)smem;                 // [MT][64] halves, linear
    _Float16* Bs = (_Float16*)(smem + MT * 64 * 2); // [128][64] halves, linear
    char* EP = smem;                                // epilogue staging (alias)
    int tid  = threadIdx.x;
    int wv   = tid >> 6;
    int lane = tid & 63;
    int quad = lane >> 4;
    int l16  = lane & 15;
    int m0 = blockIdx.x * MT;
    int n0 = blockIdx.y * 128;
    int wm = (wv >> 1) * (MT / 2);
    int wn = (wv & 1) * 64;
    constexpr int IF = MT / 32;        // row fragments per wave

    f32x4 acc[IF][4];
    #pragma unroll
    for (int i = 0; i < IF; i++)
        #pragma unroll
        for (int j = 0; j < 4; j++)
            acc[i][j] = (f32x4){0.f, 0.f, 0.f, 0.f};

    for (int k0 = 0; k0 < K; k0 += 64){
        // stage A: MT rows, MT/32 calls/wave; each call = 8 rows x 128B
        #pragma unroll
        for (int j = 0; j < MT / 32; j++){
            int rbase = wv * (MT / 4) + j * 8;
            int rrow  = rbase + (lane >> 3);
            int cgl   = (lane & 7) ^ (lane >> 3);   // global chunk (swizzled)
            gl2lds16(A + (size_t)(m0 + rrow) * K + k0 + cgl * 8, &As[rbase * 64]);
        }
        // stage B: 128 rows, 4 calls/wave
        #pragma unroll
        for (int j = 0; j < 4; j++){
            int rbase = wv * 32 + j * 8;
            int rrow  = rbase + (lane >> 3);
            int cgl   = (lane & 7) ^ (lane >> 3);
            int nr = n0 + rrow;
            if (EPI == 1) nr = nr > (DINPROJ - 1) ? (DINPROJ - 1) : nr;
            gl2lds16(Bw + (size_t)nr * K + k0 + cgl * 8, &Bs[rbase * 64]);
        }
        __syncthreads();               // vmcnt(0) drain before barrier
        #pragma unroll
        for (int kk = 0; kk < 2; kk++){
            f16x8 af[IF], bf[4];
            int sw = (l16 & 7);
            #pragma unroll
            for (int i = 0; i < IF; i++)
                af[i] = *(const f16x8*)&As[(wm + i * 16 + l16) * 64 +
                                           (((kk * 4 + quad) ^ sw) * 8)];
            #pragma unroll
            for (int j = 0; j < 4; j++)
                bf[j] = *(const f16x8*)&Bs[(wn + j * 16 + l16) * 64 +
                                           (((kk * 4 + quad) ^ sw) * 8)];
            #pragma unroll
            for (int i = 0; i < IF; i++)
                #pragma unroll
                for (int j = 0; j < 4; j++)
                    acc[i][j] = __builtin_amdgcn_mfma_f32_16x16x32_f16(
                                    af[i], bf[j], acc[i][j], 0, 0, 0);
        }
        __syncthreads();
    }

    if constexpr (EPI == 0){
        // MT==64: single-phase stage of the whole 64x128 tile as [64][136]h
        _Float16* T = (_Float16*)EP;
        #pragma unroll
        for (int i = 0; i < IF; i++){
            int row = wm + i * 16 + quad * 4;
            #pragma unroll
            for (int j = 0; j < 4; j++){
                int col = wn + j * 16 + l16;
                #pragma unroll
                for (int r = 0; r < 4; r++)
                    T[(row + r) * 136 + col] = (_Float16)acc[i][j][r];
            }
        }
        __syncthreads();
        #pragma unroll
        for (int u = 0; u < 4; u++){
            int id = u * 256 + tid;            // 0..1023
            int row = id >> 4, cc = id & 15;
            f16x8 v = *(const f16x8*)&T[row * 136 + cc * 8];
            *(f16x8*)&o_u[(size_t)(m0 + row) * DMODEL + n0 + cc * 8] = v;
        }
    } else if constexpr (EPI == 1){
        // MT==128 (proven): two phases; each stages rows {p*32..p*32+31} of
        // both 64-row halves as fp16 [2][32][136], then f16x8 coalesced stores.
        _Float16* T = (_Float16*)EP;
        #pragma unroll
        for (int p = 0; p < 2; p++){
            if (p) __syncthreads();
            {
                _Float16* Th = T + (wv >> 1) * (32 * 136);
                #pragma unroll
                for (int ii = 0; ii < 2; ii++){
                    int i = 2 * p + ii;
                    int r32 = i * 16 + quad * 4 - p * 32;   // 0..28
                    #pragma unroll
                    for (int j = 0; j < 4; j++){
                        int col = wn + j * 16 + l16;
                        #pragma unroll
                        for (int r = 0; r < 4; r++)
                            Th[(r32 + r) * 136 + col] = (_Float16)acc[i][j][r];
                    }
                }
            }
            __syncthreads();
            #pragma unroll
            for (int u = 0; u < 4; u++){
                int id = u * 256 + tid;            // 0..1023
                int hb = id >> 9, rem = id & 511;
                int r32 = rem >> 4, cc = rem & 15;
                int grow = m0 + hb * 64 + p * 32 + r32;
                int abscol = n0 + cc * 8;
                f16x8 v = *(const f16x8*)&T[hb * (32 * 136) + r32 * 136 + cc * 8];
                if (abscol < DINNER){
                    *(f16x8*)&o_z[(size_t)grow * DINNER + abscol] = v;
                } else if (abscol < DINNER + CONVDIM){
                    *(f16x8*)&o_xbc[(size_t)grow * CONVDIM + (abscol - DINNER)] = v;
                } else if (abscol < DINPROJ){
                    int hh = abscol - (DINNER + CONVDIM);
                    f16x8 o;
                    #pragma unroll
                    for (int e = 0; e < 8; e++)
                        o[e] = (_Float16)softplus_((float)v[e] + dt_bias[hh + e]);
                    *(f16x8*)&o_dt[(size_t)grow * NHEADS + hh] = o;
                }
            }
        }
    } else {
        // MT==64, transposed fp32 out: two phases of 32 rows; col-major
        // [128][36] f32 stage; acc f32x4 -> ds_write_b128; coalesced reads.
        float* Tf = (float*)EP;
        int bb = m0 >> 11, ll0 = m0 & (LEN - 1);
        #pragma unroll
        for (int q = 0; q < 2; q++){
            if (q) __syncthreads();
            if ((wv >> 1) == q){
                #pragma unroll
                for (int i = 0; i < IF; i++){
                    int r32 = i * 16 + quad * 4;            // 0..28
                    #pragma unroll
                    for (int j = 0; j < 4; j++){
                        int col = wn + j * 16 + l16;
                        *(f32x4*)&Tf[col * 36 + r32] = acc[i][j];
                    }
                }
            }
            __syncthreads();
            #pragma unroll
            for (int u = 0; u < 4; u++){
                int id = u * 256 + tid;            // 0..1023
                int col = id >> 3, seg = id & 7;
                f32x4 v = *(const f32x4*)&Tf[col * 36 + seg * 4];
                *(f32x4*)&o_f[(((size_t)(bb * DMODEL + n0 + col)) << 11)
                              + ll0 + q * 32 + seg * 4] = v;
            }
        }
    }
}

// ---------------------------------------------------------------------------
// depthwise causal conv (4-tap) + bias + SiLU, fp16 in/out (scalar form —
// measured faster than the 8-channel vectorized variant, R10 A/B).
// ---------------------------------------------------------------------------
__global__ __launch_bounds__(256) void k_dwconv(const __half* __restrict__ xbc,
                                                const float* __restrict__ cw,
                                                const float* __restrict__ cb,
                                                __half* __restrict__ xcc){
    int idx = blockIdx.x * 256 + threadIdx.x;   // < 8192*800
    int c = idx % CONVDIM;
    int r = idx / CONVDIM;
    int l = r & (LEN - 1);
    float4 wv = *(const float4*)(cw + c * 4);
    float acc = cb[c];
    if (l >= 3){
        const __half* base = xbc + (size_t)(r - 3) * CONVDIM + c;
        acc += __half2float(base[0]) * wv.x + __half2float(base[CONVDIM]) * wv.y +
               __half2float(base[2 * CONVDIM]) * wv.z + __half2float(base[3 * CONVDIM]) * wv.w;
    } else {
        const float wk[4] = {wv.x, wv.y, wv.z, wv.w};
        for (int k = 0; k < 4; k++){
            int t = l - 3 + k;
            if (t >= 0) acc += __half2float(xbc[(size_t)(r + k - 3) * CONVDIM + c]) * wk[k];
        }
    }
    xcc[idx] = __float2half(silu_(acc));
}

// ---------------------------------------------------------------------------
// k_y: chunked-SSD scan. One block per (band of 64 rows, head-quarter, b).
// ROUND-5 EXACT (56.7us measured; FETCH 8.7MB / WRITE 24.6MB): round-2
// memory structure + exp-free telescoping-product arithmetic.
// ---------------------------------------------------------------------------
__global__ __launch_bounds__(256) void k_y(const __half* __restrict__ dtb,
                                           const __half* __restrict__ xcc,
                                           const float* __restrict__ A_log,
                                           __half* __restrict__ y,
                                           float* __restrict__ E0,
                                           __half* __restrict__ cstate,
                                           float* __restrict__ dsum){
    // LDS layout (bytes):
    //   [0,4096)      sBC  [64][32]h   (B0..15 | C0..15, gl2lds linear)
    //   [4096,28672)  sX   [64][192]h  (x, premultiplied by dt after P0.5)
    //                 sHL  [3][64][48]h ALIAS over sX (written after P2)
    //   [28672,36864) sDT  [64][64]h   (raw dt, gl2lds linear)
    //   [36864,54272) sD   [64][68]f   step decay D[t][h] = exp(A_h*dt)
    //   [54272,59392) sG   [64][20]f   G[t][ss], ss = s within 16-segment
    __shared__ __align__(16) char smem[59392];
    __half* sBC = (__half*)smem;
    __half* sX  = (__half*)(smem + 4096);
    __half* sHL = (__half*)(smem + 4096);
    __half* sDT = (__half*)(smem + 28672);
    float*  sD  = (float*)(smem + 36864);
    float*  sG  = (float*)(smem + 54272);

    int band = blockIdx.x, hq = blockIdx.y, b = blockIdx.z;
    int row0 = band * BAND;
    int tid = threadIdx.x;
    int wv = tid >> 6, lane = tid & 63;

    // ---- P0: stage BC (4), X (24), DT (8) via gl2lds16, linear LDS
    {
        int c = wv, slot = c * 64 + lane;
        int row = slot >> 2, off = slot & 3;
        gl2lds16((const _Float16*)((const char*)xcc +
                   (size_t)(b * LEN + row0 + row) * 1600 + 1536 + off * 16),
                 (_Float16*)(smem + c * 1024));
    }
    #pragma unroll
    for (int i = 0; i < 6; i++){
        int c = wv + i * 4, slot = c * 64 + lane;
        int row = slot / 24, off = slot % 24;
        gl2lds16((const _Float16*)((const char*)xcc +
                   (size_t)(b * LEN + row0 + row) * 1600 + hq * 384 + off * 16),
                 (_Float16*)(smem + 4096 + c * 1024));
    }
    #pragma unroll
    for (int i = 0; i < 2; i++){
        int c = wv + i * 4, slot = c * 64 + lane;
        int row = slot >> 3, off = slot & 7;
        gl2lds16((const _Float16*)((const char*)dtb +
                   (size_t)(b * LEN + row0 + row) * 512 + hq * 128 + off * 16),
                 (_Float16*)(smem + 28672 + c * 1024));
    }
    __syncthreads();

    // ---- P0.5a: step decays D[t][h] = exp(A_h * dt[t][h])
    {
        int h = tid & 63, tb = tid >> 6;
        float A = -__expf(A_log[hq * 64 + h]);
        #pragma unroll
        for (int i = 0; i < 16; i++){
            int t = tb + i * 4;
            sD[t * 68 + h] = __expf(A * __half2float(sDT[t * 64 + h]));
        }
    }
    __syncthreads();

    // ---- P0.5b: E0 prefix-product (0..63) | G dots (64..127) | x*=dt (128..255)
    if (tid < 64){
        int h = tid;
        float E = 1.f;
        float* ep = E0 + ((size_t)(b * LEN + row0)) * 256 + hq * 64 + h;
        for (int t = 0; t < 64; t++){
            E *= sD[t * 68 + h];
            *ep = E;
            ep += 256;
        }
        dsum[(size_t)(b * 256 + hq * 64 + h) * NBAND + band] = E;
    } else if (tid < 128){
        int tt = tid - 64;                       // one t row: 16 dots
        f16x8 ca = *(const f16x8*)&sBC[tt * 32 + 16];
        f16x8 cb = *(const f16x8*)&sBC[tt * 32 + 24];
        float cf[16];
        #pragma unroll
        for (int n = 0; n < 16; n++) cf[n] = (n < 8) ? (float)ca[n] : (float)cb[n - 8];
        for (int ss = 0; ss < 16; ss++){
            int s = (tt & 48) + ss;
            f16x8 ba = *(const f16x8*)&sBC[s * 32];
            f16x8 bb = *(const f16x8*)&sBC[s * 32 + 8];
            float acc = 0.f;
            #pragma unroll
            for (int n = 0; n < 8; n++)
                acc += cf[n] * (float)ba[n] + cf[n + 8] * (float)bb[n];
            sG[tt * 20 + ss] = acc;
        }
    } else {
        for (int idx = tid - 128; idx < 4096; idx += 128){
            int t = idx >> 6, h = idx & 63;
            float dtv = __half2float(sDT[t * 64 + h]);
            int xi = t * 192 + h * 3;
            sX[xi]     = __float2half(__half2float(sX[xi])     * dtv);
            sX[xi + 1] = __float2half(__half2float(sX[xi + 1]) * dtv);
            sX[xi + 2] = __float2half(__half2float(sX[xi + 2]) * dtv);
        }
    }
    __syncthreads();

    // ---- P1: within-segment masked pair sum via running decay products
    int t = tid >> 2, hsub = tid & 3, Hb = hsub * 16;
    int tmod = t & 15;
    float w[16], y0[16], y1[16], y2[16];
    #pragma unroll
    for (int i = 0; i < 16; i++){ w[i] = 1.f; y0[i] = 0.f; y1[i] = 0.f; y2[i] = 0.f; }

    for (int d = 0; d <= tmod; d++){
        int s = t - d;
        float g = sG[t * 20 + (tmod - d)];
        f32x4 Dv[4];
        #pragma unroll
        for (int k4 = 0; k4 < 4; k4++)
            Dv[k4] = *(const f32x4*)&sD[s * 68 + Hb + k4 * 4];
        f16x8 xv0 = *(const f16x8*)&sX[s * 192 + Hb * 3];
        f16x8 xv1 = *(const f16x8*)&sX[s * 192 + Hb * 3 + 8];
        f16x8 xv2 = *(const f16x8*)&sX[s * 192 + Hb * 3 + 16];
        f16x8 xv3 = *(const f16x8*)&sX[s * 192 + Hb * 3 + 24];
        f16x8 xv4 = *(const f16x8*)&sX[s * 192 + Hb * 3 + 32];
        f16x8 xv5 = *(const f16x8*)&sX[s * 192 + Hb * 3 + 40];
        #define XV(i) ((i)<8?(float)xv0[(i)]:(i)<16?(float)xv1[(i)-8]:(i)<24?(float)xv2[(i)-16]:\
                       (i)<32?(float)xv3[(i)-24]:(i)<40?(float)xv4[(i)-32]:(float)xv5[(i)-40])
        #pragma unroll
        for (int hh = 0; hh < 16; hh++){
            float wg = w[hh] * g;
            y0[hh] = fmaf(wg, XV(hh * 3 + 0), y0[hh]);
            y1[hh] = fmaf(wg, XV(hh * 3 + 1), y1[hh]);
            y2[hh] = fmaf(wg, XV(hh * 3 + 2), y2[hh]);
            w[hh] *= Dv[hh >> 2][hh & 3];
        }
        #undef XV
    }
    // after loop: w[hh] = exp(a_t - a_{tseg-1})  (used in P3)

    // ---- P2: segment-final states (reads only), all 256 threads
    int h2 = tid >> 2, ng = tid & 3;
    float F[4][12];
    float vK[4];
    #pragma unroll
    for (int k = 0; k < 4; k++){
        #pragma unroll
        for (int i = 0; i < 12; i++) F[k][i] = 0.f;
        float v = 1.f;
        for (int ss = 15; ss >= 0; ss--){
            int s = k * 16 + ss;
            float x0 = __half2float(sX[s * 192 + h2 * 3]);
            float x1 = __half2float(sX[s * 192 + h2 * 3 + 1]);
            float x2 = __half2float(sX[s * 192 + h2 * 3 + 2]);
            f16x4 bv = *(const f16x4*)&sBC[s * 32 + ng * 4];
            #pragma unroll
            for (int nn = 0; nn < 4; nn++){
                float wb = v * (float)bv[nn];
                F[k][nn * 3 + 0] = fmaf(wb, x0, F[k][nn * 3 + 0]);
                F[k][nn * 3 + 1] = fmaf(wb, x1, F[k][nn * 3 + 1]);
                F[k][nn * 3 + 2] = fmaf(wb, x2, F[k][nn * 3 + 2]);
            }
            v *= sD[s * 68 + h2];
        }
        vK[k] = v;                     // segment decay
    }

    __syncthreads();   // all LDS reads of sX done before sHL overwrite

    // ---- P2b: chain boundary states; write sHL[0..2], cstate
    {
        float hc[12];
        #pragma unroll
        for (int i = 0; i < 12; i++) hc[i] = F[0][i];
        #pragma unroll
        for (int i = 0; i < 12; i++)
            sHL[(0 * 64 + h2) * 48 + ng * 12 + i] = __float2half(hc[i]);
        #pragma unroll
        for (int k = 1; k <= 2; k++){
            #pragma unroll
            for (int i = 0; i < 12; i++) hc[i] = fmaf(vK[k], hc[i], F[k][i]);
            #pragma unroll
            for (int i = 0; i < 12; i++)
                sHL[(k * 64 + h2) * 48 + ng * 12 + i] = __float2half(hc[i]);
        }
        __half* cp = cstate + ((size_t)((b * 256 + hq * 64 + h2) * NBAND + band)) * 48 + ng * 12;
        #pragma unroll
        for (int i = 0; i < 12; i++)
            cp[i] = __float2half(fmaf(vK[3], hc[i], F[3][i]));
    }
    __syncthreads();

    // ---- P3: cross-segment terms (coeff = w from P1) + y store
    {
        f16x8 cva = *(const f16x8*)&sBC[t * 32 + 16];
        f16x8 cvb = *(const f16x8*)&sBC[t * 32 + 24];
        float cf[16];
        #pragma unroll
        for (int n = 0; n < 16; n++) cf[n] = (n < 8) ? (float)cva[n] : (float)cvb[n - 8];
        int k = t >> 4;
        if (k > 0){
            #pragma unroll
            for (int hh = 0; hh < 16; hh++){
                int h = Hb + hh;
                const __half* hl = &sHL[((k - 1) * 64 + h) * 48];
                f16x8 hv0 = *(const f16x8*)&hl[0];
                f16x8 hv1 = *(const f16x8*)&hl[8];
                f16x8 hv2 = *(const f16x8*)&hl[16];
                f16x8 hv3 = *(const f16x8*)&hl[24];
                f16x8 hv4 = *(const f16x8*)&hl[32];
                f16x8 hv5 = *(const f16x8*)&hl[40];
                #define HV(i) ((i)<8?(float)hv0[(i)]:(i)<16?(float)hv1[(i)-8]:(i)<24?(float)hv2[(i)-16]:\
                               (i)<32?(float)hv3[(i)-24]:(i)<40?(float)hv4[(i)-32]:(float)hv5[(i)-40])
                float a0 = 0.f, a1 = 0.f, a2 = 0.f;
                #pragma unroll
                for (int n = 0; n < 16; n++){
                    a0 = fmaf(cf[n], HV(n * 3 + 0), a0);
                    a1 = fmaf(cf[n], HV(n * 3 + 1), a1);
                    a2 = fmaf(cf[n], HV(n * 3 + 2), a2);
                }
                #undef HV
                y0[hh] = fmaf(w[hh], a0, y0[hh]);
                y1[hh] = fmaf(w[hh], a1, y1[hh]);
                y2[hh] = fmaf(w[hh], a2, y2[hh]);
            }
        }
        __half* yp = y + (size_t)(b * LEN + row0 + t) * DINNER + hq * 192 + hsub * 48;
        #pragma unroll
        for (int c = 0; c < 6; c++){
            f16x8 pk;
            #pragma unroll
            for (int e2 = 0; e2 < 8; e2++){
                int gi = c * 8 + e2;
                int hh = gi / 3, p = gi % 3;
                pk[e2] = (_Float16)(p == 0 ? y0[hh] : (p == 1 ? y1[hh] : y2[hh]));
            }
            *(f16x8*)&yp[c * 8] = pk;
        }
    }
}

// ---------------------------------------------------------------------------
// scan pass B: per (b,h), combine band summaries sequentially; overwrite
// cstate[band] in place with the INITIAL state of that band.
// ---------------------------------------------------------------------------
__global__ __launch_bounds__(64) void k_scanB(__half* __restrict__ cstate,
                                              const float* __restrict__ dsum){
    int bh = blockIdx.x;               // 0..1023
    int lane = threadIdx.x;
    if (lane >= 48) return;
    __half* st = cstate + (size_t)bh * NBAND * 48 + lane;
    const float* dd = dsum + (size_t)bh * NBAND;
    float H = 0.f;
    for (int c = 0; c < NBAND; c++){
        float d = dd[c];
        float s = __half2float(st[(size_t)c * 48]);
        st[(size_t)c * 48] = __float2half(H);
        H = fmaf(H, d, s);
    }
}

// ---------------------------------------------------------------------------
// fused correction + gated RMSNorm:
//   y_full = y_scan + E0*(C . h_band_init) + D_skip*x
//   y_out  = (y_full * silu(z)) * rsqrt(mean(sq)+eps) * nw
// One block per row; h_init for the row's band staged in LDS (L2-hot).
// ---------------------------------------------------------------------------
__global__ __launch_bounds__(256) void k_norm(__half* __restrict__ y,
                                              const __half* __restrict__ z,
                                              const __half* __restrict__ xcc,
                                              const float* __restrict__ E0,
                                              const __half* __restrict__ cstate,
                                              const float* __restrict__ D_skip,
                                              const float* __restrict__ nw){
    __shared__ __align__(16) char nsm[24576 + 64];
    __half* sHI = (__half*)nsm;                 // [256][48]
    float*  sCf = (float*)(nsm + 24576);        // [16]
    __shared__ float wsum[4];
    int r = blockIdx.x;
    int b = r >> 11, l = r & (LEN - 1), band = l >> 6;
    int tid = threadIdx.x;
    int wv = tid >> 6, lane = tid & 63;

    #pragma unroll
    for (int i = 0; i < 6; i++){
        int chunk = (wv + i * 4) * 64 + lane;    // 0..1535
        int head = chunk / 6, off = chunk % 6;
        gl2lds16((const _Float16*)((const char*)cstate +
                   ((size_t)(b * 256 + head) * NBAND + band) * 96 + off * 16),
                 (_Float16*)(nsm + (wv + i * 4) * 1024));
    }
    if (tid < 16)
        sCf[tid] = __half2float(xcc[(size_t)r * CONVDIM + DINNER + DSTATE + tid]);
    __syncthreads();

    const __half* zr = z + (size_t)r * DINNER;
    const __half* xr = xcc + (size_t)r * CONVDIM;
    const float*  er = E0 + (size_t)r * 256;
    __half* yr = y + (size_t)r * DINNER;
    float tv[3];
    #pragma unroll
    for (int q = 0; q < 3; q++){
        int e = tid + q * 256;
        int h = e / 3, p = e - h * 3;
        float corr = 0.f;
        #pragma unroll
        for (int n = 0; n < 16; n++)
            corr = fmaf(sCf[n], __half2float(sHI[h * 48 + n * 3 + p]), corr);
        float yf = __half2float(yr[e]) + er[h] * corr + D_skip[h] * __half2float(xr[e]);
        tv[q] = yf * silu_(__half2float(zr[e]));
    }
    float ss = tv[0] * tv[0] + tv[1] * tv[1] + tv[2] * tv[2];
    #pragma unroll
    for (int m = 1; m < 64; m <<= 1) ss += __shfl_xor(ss, m, 64);
    if ((tid & 63) == 0) wsum[tid >> 6] = ss;
    __syncthreads();
    float tot = wsum[0] + wsum[1] + wsum[2] + wsum[3];
    float sc = rsqrtf(tot / (float)DINNER + EPS_);
    #pragma unroll
    for (int q = 0; q < 3; q++){
        int e = tid + q * 256;
        yr[e] = __float2half(tv[q] * sc * nw[e]);
    }
}

// ---------------------------------------------------------------------------
extern "C" void kernel_launch(void* const* d_in, const int* in_sizes, int n_in,
                              void* d_out, int out_size, void* d_ws, size_t ws_size,
                              hipStream_t stream) {
    const float* x          = (const float*)d_in[0];
    const float* proj_w     = (const float*)d_in[1];
    const float* in_proj_w  = (const float*)d_in[2];
    const float* conv_w     = (const float*)d_in[3];
    const float* conv_b     = (const float*)d_in[4];
    const float* dt_bias    = (const float*)d_in[5];
    const float* A_log      = (const float*)d_in[6];
    const float* D_skip     = (const float*)d_in[7];
    const float* norm_w     = (const float*)d_in[8];
    const float* out_proj_w = (const float*)d_in[9];
    float* out = (float*)d_out;

    // d_out (8 MB) triple-duty:
    //   1) fp16 proj/in_proj weights (dead after gemm<256,1>)
    //   2) E0 = exp(A*cum) fp32 [8192][256] (k_y..k_norm)
    //   3) final output (gemm<768,2> overwrites everything)
    char* ob = (char*)d_out;
    _Float16* pw_h  = (_Float16*)ob;                   //   262,144 B (256x512)
    _Float16* ipw_h = (_Float16*)(ob + 262144);        //   933,888 B (1824x256)
    float*    E0    = (float*)d_out;                   // 8,388,608 B exactly

    char* wsb = (char*)d_ws;
    _Float16* xcol  = (_Float16*)(wsb);                // 8192x512 fp16
    _Float16* u_h   = (_Float16*)(wsb + 8388608);      // 8192x256 fp16
    __half*   xcc_h = (__half*)(wsb);                  // 8192x800 fp16 (alias)
    __half*   z_h   = (__half*)(wsb + 13107200);       // 8192x768
    __half*   xbc_h = (__half*)(wsb + 25690112);       // 8192x800
    __half*   y_h   = xbc_h;                           // alias: xbc dead after dwconv
    __half*   dt_h  = (__half*)(wsb + 38797312);       // 8192x256
    __half*   cstate= (__half*)(wsb + 42991616);       // 1024*32*48 fp16 (3.1MB)
    float*    dsum  = (float*)(wsb + 46137344);        // 1024*32 f32
    _Float16* opw_h = (_Float16*)(wsb + 46268416);     // 256x768 fp16 -> total 46,661,632

    k_f2h3  <<<128, 256, 0, stream>>>(proj_w, pw_h, DMODEL * CIN * 4,
                                      in_proj_w, ipw_h, DINPROJ * DMODEL,
                                      out_proj_w, opw_h, DMODEL * DINNER);
    k_im2col<<<128, 256, 0, stream>>>(x, xcol);
    k_gemm<512, 0, 64><<<dim3(128, 2), 256, 0, stream>>>(xcol, pw_h, nullptr,
        u_h, nullptr, nullptr, nullptr, nullptr);
    k_gemm<256, 1, 128><<<dim3(64, 15), 256, 0, stream>>>(u_h, ipw_h, dt_bias,
        nullptr, (_Float16*)z_h, (_Float16*)xbc_h, (_Float16*)dt_h, nullptr);
    k_dwconv<<<25600, 256, 0, stream>>>(xbc_h, conv_w, conv_b, xcc_h);
    k_y     <<<dim3(NBAND, 4, B_), 256, 0, stream>>>(dt_h, xcc_h, A_log,
                                                     y_h, E0, cstate, dsum);
    k_scanB <<<1024, 64, 0, stream>>>(cstate, dsum);
    k_norm  <<<8192, 256, 0, stream>>>(y_h, z_h, xcc_h, E0, cstate,
                                       D_skip, norm_w);
    k_gemm<768, 2, 64><<<dim3(128, 2), 256, 0, stream>>>((const _Float16*)y_h, opw_h,
        nullptr, nullptr, nullptr, nullptr, nullptr, out);
}

// Round 14
// 282.683 us; speedup vs baseline: 1.2648x; 1.2648x over previous
//
#include <hip/hip_runtime.h>
#include <hip/hip_fp16.h>
#include <math.h>

// Problem constants
#define B_     4
#define CIN    128
#define LEN    2048
#define DMODEL 256
#define DSTATE 16
#define NHEADS 256
#define DINNER 768
#define CONVDIM 800      // DINNER + 2*DSTATE
#define DINPROJ 1824     // 2*DINNER + 2*DSTATE + NHEADS
#define EPS_   1e-5f
#define BAND   64        // rows per k_y block
#define NBAND  32        // LEN / BAND

typedef _Float16 f16x8 __attribute__((ext_vector_type(8)));
typedef _Float16 f16x4 __attribute__((ext_vector_type(4)));
typedef float    f32x4 __attribute__((ext_vector_type(4)));

__device__ __forceinline__ float silu_(float x){ return x / (1.0f + __expf(-x)); }
__device__ __forceinline__ float softplus_(float x){
    return x > 0.f ? x + log1pf(__expf(-x)) : log1pf(__expf(x));
}

// async global->LDS, 16B per lane; LDS dest = wave-uniform base + lane*16
__device__ __forceinline__ void gl2lds16(const _Float16* g, _Float16* l){
    __builtin_amdgcn_global_load_lds(
        (const __attribute__((address_space(1))) void*)g,
        (__attribute__((address_space(3))) void*)l, 16, 0, 0);
}

// ---------------------------------------------------------------------------
// fp32 -> fp16 convert for the three weight tensors, one launch
// ---------------------------------------------------------------------------
__global__ __launch_bounds__(256) void k_f2h3(const float* __restrict__ a0,
                                              _Float16* __restrict__ o0, int n0,
                                              const float* __restrict__ a1,
                                              _Float16* __restrict__ o1, int n1,
                                              const float* __restrict__ a2,
                                              _Float16* __restrict__ o2, int n2){
    int stride = gridDim.x * 256;
    for (int i = blockIdx.x * 256 + threadIdx.x; i < n0; i += stride)
        o0[i] = (_Float16)a0[i];
    for (int i = blockIdx.x * 256 + threadIdx.x; i < n1; i += stride)
        o1[i] = (_Float16)a1[i];
    for (int i = blockIdx.x * 256 + threadIdx.x; i < n2; i += stride)
        o2[i] = (_Float16)a2[i];
}

// ---------------------------------------------------------------------------
// im2col for the conv projection: xcol[(b,l)][(ci,k)] = x[b,ci,l-1+k], fp16.
// ---------------------------------------------------------------------------
__global__ __launch_bounds__(256) void k_im2col(const float* __restrict__ x,
                                                _Float16* __restrict__ xcol){
    __shared__ float xs[CIN][68];      // 67 used
    int blk = blockIdx.x;              // 0..127
    int b  = blk >> 5;
    int l0 = (blk & 31) << 6;          // *64
    const float* xb = x + (size_t)b * CIN * LEN;
    for (int idx = threadIdx.x; idx < CIN * 67; idx += 256){
        int ci = idx / 67, j = idx % 67;
        int gl = l0 - 1 + j;
        xs[ci][j] = (gl >= 0 && gl < LEN) ? xb[ci * LEN + gl] : 0.f;
    }
    __syncthreads();
    #pragma unroll
    for (int v = 0; v < 16; v++){
        int id = v * 256 + threadIdx.x;   // 0..4095
        int rl = id >> 6, c = id & 63;    // row-in-tile, 16B chunk
        f16x8 pk;
        #pragma unroll
        for (int e = 0; e < 8; e++){
            int ci = c * 2 + (e >> 2), k = e & 3;
            pk[e] = (_Float16)xs[ci][rl + k];
        }
        *(f16x8*)&xcol[((size_t)(b * LEN + l0 + rl)) * 512 + c * 8] = pk;
    }
}

// ---------------------------------------------------------------------------
// Shared MFMA GEMM: C[M][N] = A[M][K] . Bw[N][K]^T, f16 inputs, fp32 acc.
// BK=64 (half the barrier drains of BK=32); LDS rows are 128B so fragment
// reads XOR-swizzle the chunk index (rule: linear gl2lds dest + inverse-
// swizzled global source + same swizzle on read). Epilogues stage the tile
// through LDS (EP aliases As/Bs, dead after the K loop) -> 16B coalesced
// global stores only.
// ---------------------------------------------------------------------------
template<int K, int EPI>
__global__ __launch_bounds__(256) void k_gemm(const _Float16* __restrict__ A,
                                              const _Float16* __restrict__ Bw,
                                              const float* __restrict__ dt_bias,
                                              _Float16* __restrict__ o_u,
                                              _Float16* __restrict__ o_z,
                                              _Float16* __restrict__ o_xbc,
                                              _Float16* __restrict__ o_dt,
                                              float* __restrict__ o_f){
    __shared__ __align__(16) char smem[32768];
    _Float16* As = (_Float16*)smem;            // [128][64] halves, linear
    _Float16* Bs = (_Float16*)(smem + 16384);  // [128][64] halves, linear
    char* EP = smem;                           // epilogue staging (alias)
    int tid  = threadIdx.x;
    int wv   = tid >> 6;
    int lane = tid & 63;
    int quad = lane >> 4;
    int l16  = lane & 15;
    int m0 = blockIdx.x * 128;
    int n0 = blockIdx.y * 128;
    int wm = (wv >> 1) * 64;
    int wn = (wv & 1) * 64;

    f32x4 acc[4][4];
    #pragma unroll
    for (int i = 0; i < 4; i++)
        #pragma unroll
        for (int j = 0; j < 4; j++)
            acc[i][j] = (f32x4){0.f, 0.f, 0.f, 0.f};

    for (int k0 = 0; k0 < K; k0 += 64){
        // stage: 4 instructions per wave per matrix; lane covers row
        // rbase+(lane>>3), physical chunk lane&7 <- global chunk xor'd
        #pragma unroll
        for (int j = 0; j < 4; j++){
            int rbase = wv * 32 + j * 8;
            int rrow  = rbase + (lane >> 3);
            int cgl   = (lane & 7) ^ (lane >> 3);   // global chunk (swizzled)
            int ar = m0 + rrow;
            gl2lds16(A + (size_t)ar * K + k0 + cgl * 8, &As[rbase * 64]);
            int nr = n0 + rrow;
            if (EPI == 1) nr = nr > (DINPROJ - 1) ? (DINPROJ - 1) : nr;
            gl2lds16(Bw + (size_t)nr * K + k0 + cgl * 8, &Bs[rbase * 64]);
        }
        __syncthreads();               // vmcnt(0) drain before barrier
        #pragma unroll
        for (int kk = 0; kk < 2; kk++){
            f16x8 af[4], bf[4];
            int sw = (l16 & 7);
            #pragma unroll
            for (int i = 0; i < 4; i++)
                af[i] = *(const f16x8*)&As[(wm + i * 16 + l16) * 64 +
                                           (((kk * 4 + quad) ^ sw) * 8)];
            #pragma unroll
            for (int j = 0; j < 4; j++)
                bf[j] = *(const f16x8*)&Bs[(wn + j * 16 + l16) * 64 +
                                           (((kk * 4 + quad) ^ sw) * 8)];
            #pragma unroll
            for (int i = 0; i < 4; i++)
                #pragma unroll
                for (int j = 0; j < 4; j++)
                    acc[i][j] = __builtin_amdgcn_mfma_f32_16x16x32_f16(
                                    af[i], bf[j], acc[i][j], 0, 0, 0);
        }
        __syncthreads();
    }

    if (EPI == 0 || EPI == 1){
        // two phases; each stages rows {p*32..p*32+31} of both 64-row halves
        // as fp16 [2][32][136] then streams f16x8 coalesced stores.
        _Float16* T = (_Float16*)EP;
        #pragma unroll
        for (int p = 0; p < 2; p++){
            if (p) __syncthreads();
            {
                _Float16* Th = T + (wv >> 1) * (32 * 136);
                #pragma unroll
                for (int ii = 0; ii < 2; ii++){
                    int i = 2 * p + ii;
                    int r32 = i * 16 + quad * 4 - p * 32;   // 0..28
                    #pragma unroll
                    for (int j = 0; j < 4; j++){
                        int col = wn + j * 16 + l16;
                        #pragma unroll
                        for (int r = 0; r < 4; r++)
                            Th[(r32 + r) * 136 + col] = (_Float16)acc[i][j][r];
                    }
                }
            }
            __syncthreads();
            #pragma unroll
            for (int u = 0; u < 4; u++){
                int id = u * 256 + tid;            // 0..1023
                int hb = id >> 9, rem = id & 511;
                int r32 = rem >> 4, cc = rem & 15;
                int grow = m0 + hb * 64 + p * 32 + r32;
                int abscol = n0 + cc * 8;
                f16x8 v = *(const f16x8*)&T[hb * (32 * 136) + r32 * 136 + cc * 8];
                if (EPI == 0){
                    *(f16x8*)&o_u[(size_t)grow * DMODEL + abscol] = v;
                } else {
                    if (abscol < DINNER){
                        *(f16x8*)&o_z[(size_t)grow * DINNER + abscol] = v;
                    } else if (abscol < DINNER + CONVDIM){
                        *(f16x8*)&o_xbc[(size_t)grow * CONVDIM + (abscol - DINNER)] = v;
                    } else if (abscol < DINPROJ){
                        int hh = abscol - (DINNER + CONVDIM);
                        f16x8 o;
                        #pragma unroll
                        for (int e = 0; e < 8; e++)
                            o[e] = (_Float16)softplus_((float)v[e] + dt_bias[hh + e]);
                        *(f16x8*)&o_dt[(size_t)grow * NHEADS + hh] = o;
                    }
                }
            }
        }
    } else {
        // transposed fp32 out: 4 quarters of 32 rows, col-major [128][36] f32;
        // acc f32x4 = 4 consecutive rows -> single ds_write_b128; reads are
        // 128B-per-column coalesced f32x4 runs.
        float* Tf = (float*)EP;
        int bb = m0 >> 11, ll0 = m0 & (LEN - 1);
        #pragma unroll
        for (int q = 0; q < 4; q++){
            if (q) __syncthreads();
            if ((wv >> 1) == (q >> 1)){
                #pragma unroll
                for (int ii = 0; ii < 2; ii++){
                    int i = (q & 1) * 2 + ii;
                    int r32 = i * 16 + quad * 4 - (q & 1) * 32;  // 0..28
                    #pragma unroll
                    for (int j = 0; j < 4; j++){
                        int col = wn + j * 16 + l16;
                        *(f32x4*)&Tf[col * 36 + r32] = acc[i][j];
                    }
                }
            }
            __syncthreads();
            #pragma unroll
            for (int u = 0; u < 4; u++){
                int id = u * 256 + tid;            // 0..1023
                int col = id >> 3, seg = id & 7;
                f32x4 v = *(const f32x4*)&Tf[col * 36 + seg * 4];
                *(f32x4*)&o_f[(((size_t)(bb * DMODEL + n0 + col)) << 11)
                              + ll0 + q * 32 + seg * 4] = v;
            }
        }
    }
}

// ---------------------------------------------------------------------------
// depthwise causal conv (4-tap) + bias + SiLU, fp16 in/out (scalar form —
// measured faster than the 8-channel vectorized variant, R10 A/B).
// ---------------------------------------------------------------------------
__global__ __launch_bounds__(256) void k_dwconv(const __half* __restrict__ xbc,
                                                const float* __restrict__ cw,
                                                const float* __restrict__ cb,
                                                __half* __restrict__ xcc){
    int idx = blockIdx.x * 256 + threadIdx.x;   // < 8192*800
    int c = idx % CONVDIM;
    int r = idx / CONVDIM;
    int l = r & (LEN - 1);
    float4 wv = *(const float4*)(cw + c * 4);
    float acc = cb[c];
    if (l >= 3){
        const __half* base = xbc + (size_t)(r - 3) * CONVDIM + c;
        acc += __half2float(base[0]) * wv.x + __half2float(base[CONVDIM]) * wv.y +
               __half2float(base[2 * CONVDIM]) * wv.z + __half2float(base[3 * CONVDIM]) * wv.w;
    } else {
        const float wk[4] = {wv.x, wv.y, wv.z, wv.w};
        for (int k = 0; k < 4; k++){
            int t = l - 3 + k;
            if (t >= 0) acc += __half2float(xbc[(size_t)(r + k - 3) * CONVDIM + c]) * wk[k];
        }
    }
    xcc[idx] = __float2half(silu_(acc));
}

// ---------------------------------------------------------------------------
// k_y: chunked-SSD scan. One block per (band of 64 rows, head-quarter, b).
// ROUND-5 EXACT (56.7us measured; FETCH 8.7MB / WRITE 24.6MB): round-2
// memory structure + exp-free telescoping-product arithmetic.
// ---------------------------------------------------------------------------
__global__ __launch_bounds__(256) void k_y(const __half* __restrict__ dtb,
                                           const __half* __restrict__ xcc,
                                           const float* __restrict__ A_log,
                                           __half* __restrict__ y,
                                           float* __restrict__ E0,
                                           __half* __restrict__ cstate,
                                           float* __restrict__ dsum){
    // LDS layout (bytes):
    //   [0,4096)      sBC  [64][32]h   (B0..15 | C0..15, gl2lds linear)
    //   [4096,28672)  sX   [64][192]h  (x, premultiplied by dt after P0.5)
    //                 sHL  [3][64][48]h ALIAS over sX (written after P2)
    //   [28672,36864) sDT  [64][64]h   (raw dt, gl2lds linear)
    //   [36864,54272) sD   [64][68]f   step decay D[t][h] = exp(A_h*dt)
    //   [54272,59392) sG   [64][20]f   G[t][ss], ss = s within 16-segment
    __shared__ __align__(16) char smem[59392];
    __half* sBC = (__half*)smem;
    __half* sX  = (__half*)(smem + 4096);
    __half* sHL = (__half*)(smem + 4096);
    __half* sDT = (__half*)(smem + 28672);
    float*  sD  = (float*)(smem + 36864);
    float*  sG  = (float*)(smem + 54272);

    int band = blockIdx.x, hq = blockIdx.y, b = blockIdx.z;
    int row0 = band * BAND;
    int tid = threadIdx.x;
    int wv = tid >> 6, lane = tid & 63;

    // ---- P0: stage BC (4), X (24), DT (8) via gl2lds16, linear LDS
    {
        int c = wv, slot = c * 64 + lane;
        int row = slot >> 2, off = slot & 3;
        gl2lds16((const _Float16*)((const char*)xcc +
                   (size_t)(b * LEN + row0 + row) * 1600 + 1536 + off * 16),
                 (_Float16*)(smem + c * 1024));
    }
    #pragma unroll
    for (int i = 0; i < 6; i++){
        int c = wv + i * 4, slot = c * 64 + lane;
        int row = slot / 24, off = slot % 24;
        gl2lds16((const _Float16*)((const char*)xcc +
                   (size_t)(b * LEN + row0 + row) * 1600 + hq * 384 + off * 16),
                 (_Float16*)(smem + 4096 + c * 1024));
    }
    #pragma unroll
    for (int i = 0; i < 2; i++){
        int c = wv + i * 4, slot = c * 64 + lane;
        int row = slot >> 3, off = slot & 7;
        gl2lds16((const _Float16*)((const char*)dtb +
                   (size_t)(b * LEN + row0 + row) * 512 + hq * 128 + off * 16),
                 (_Float16*)(smem + 28672 + c * 1024));
    }
    __syncthreads();

    // ---- P0.5a: step decays D[t][h] = exp(A_h * dt[t][h])
    {
        int h = tid & 63, tb = tid >> 6;
        float A = -__expf(A_log[hq * 64 + h]);
        #pragma unroll
        for (int i = 0; i < 16; i++){
            int t = tb + i * 4;
            sD[t * 68 + h] = __expf(A * __half2float(sDT[t * 64 + h]));
        }
    }
    __syncthreads();

    // ---- P0.5b: E0 prefix-product (0..63) | G dots (64..127) | x*=dt (128..255)
    if (tid < 64){
        int h = tid;
        float E = 1.f;
        float* ep = E0 + ((size_t)(b * LEN + row0)) * 256 + hq * 64 + h;
        for (int t = 0; t < 64; t++){
            E *= sD[t * 68 + h];
            *ep = E;
            ep += 256;
        }
        dsum[(size_t)(b * 256 + hq * 64 + h) * NBAND + band] = E;
    } else if (tid < 128){
        int tt = tid - 64;                       // one t row: 16 dots
        f16x8 ca = *(const f16x8*)&sBC[tt * 32 + 16];
        f16x8 cb = *(const f16x8*)&sBC[tt * 32 + 24];
        float cf[16];
        #pragma unroll
        for (int n = 0; n < 16; n++) cf[n] = (n < 8) ? (float)ca[n] : (float)cb[n - 8];
        for (int ss = 0; ss < 16; ss++){
            int s = (tt & 48) + ss;
            f16x8 ba = *(const f16x8*)&sBC[s * 32];
            f16x8 bb = *(const f16x8*)&sBC[s * 32 + 8];
            float acc = 0.f;
            #pragma unroll
            for (int n = 0; n < 8; n++)
                acc += cf[n] * (float)ba[n] + cf[n + 8] * (float)bb[n];
            sG[tt * 20 + ss] = acc;
        }
    } else {
        for (int idx = tid - 128; idx < 4096; idx += 128){
            int t = idx >> 6, h = idx & 63;
            float dtv = __half2float(sDT[t * 64 + h]);
            int xi = t * 192 + h * 3;
            sX[xi]     = __float2half(__half2float(sX[xi])     * dtv);
            sX[xi + 1] = __float2half(__half2float(sX[xi + 1]) * dtv);
            sX[xi + 2] = __float2half(__half2float(sX[xi + 2]) * dtv);
        }
    }
    __syncthreads();

    // ---- P1: within-segment masked pair sum via running decay products
    int t = tid >> 2, hsub = tid & 3, Hb = hsub * 16;
    int tmod = t & 15;
    float w[16], y0[16], y1[16], y2[16];
    #pragma unroll
    for (int i = 0; i < 16; i++){ w[i] = 1.f; y0[i] = 0.f; y1[i] = 0.f; y2[i] = 0.f; }

    for (int d = 0; d <= tmod; d++){
        int s = t - d;
        float g = sG[t * 20 + (tmod - d)];
        f32x4 Dv[4];
        #pragma unroll
        for (int k4 = 0; k4 < 4; k4++)
            Dv[k4] = *(const f32x4*)&sD[s * 68 + Hb + k4 * 4];
        f16x8 xv0 = *(const f16x8*)&sX[s * 192 + Hb * 3];
        f16x8 xv1 = *(const f16x8*)&sX[s * 192 + Hb * 3 + 8];
        f16x8 xv2 = *(const f16x8*)&sX[s * 192 + Hb * 3 + 16];
        f16x8 xv3 = *(const f16x8*)&sX[s * 192 + Hb * 3 + 24];
        f16x8 xv4 = *(const f16x8*)&sX[s * 192 + Hb * 3 + 32];
        f16x8 xv5 = *(const f16x8*)&sX[s * 192 + Hb * 3 + 40];
        #define XV(i) ((i)<8?(float)xv0[(i)]:(i)<16?(float)xv1[(i)-8]:(i)<24?(float)xv2[(i)-16]:\
                       (i)<32?(float)xv3[(i)-24]:(i)<40?(float)xv4[(i)-32]:(float)xv5[(i)-40])
        #pragma unroll
        for (int hh = 0; hh < 16; hh++){
            float wg = w[hh] * g;
            y0[hh] = fmaf(wg, XV(hh * 3 + 0), y0[hh]);
            y1[hh] = fmaf(wg, XV(hh * 3 + 1), y1[hh]);
            y2[hh] = fmaf(wg, XV(hh * 3 + 2), y2[hh]);
            w[hh] *= Dv[hh >> 2][hh & 3];
        }
        #undef XV
    }
    // after loop: w[hh] = exp(a_t - a_{tseg-1})  (used in P3)

    // ---- P2: segment-final states (reads only), all 256 threads
    int h2 = tid >> 2, ng = tid & 3;
    float F[4][12];
    float vK[4];
    #pragma unroll
    for (int k = 0; k < 4; k++){
        #pragma unroll
        for (int i = 0; i < 12; i++) F[k][i] = 0.f;
        float v = 1.f;
        for (int ss = 15; ss >= 0; ss--){
            int s = k * 16 + ss;
            float x0 = __half2float(sX[s * 192 + h2 * 3]);
            float x1 = __half2float(sX[s * 192 + h2 * 3 + 1]);
            float x2 = __half2float(sX[s * 192 + h2 * 3 + 2]);
            f16x4 bv = *(const f16x4*)&sBC[s * 32 + ng * 4];
            #pragma unroll
            for (int nn = 0; nn < 4; nn++){
                float wb = v * (float)bv[nn];
                F[k][nn * 3 + 0] = fmaf(wb, x0, F[k][nn * 3 + 0]);
                F[k][nn * 3 + 1] = fmaf(wb, x1, F[k][nn * 3 + 1]);
                F[k][nn * 3 + 2] = fmaf(wb, x2, F[k][nn * 3 + 2]);
            }
            v *= sD[s * 68 + h2];
        }
        vK[k] = v;                     // segment decay
    }

    __syncthreads();   // all LDS reads of sX done before sHL overwrite

    // ---- P2b: chain boundary states; write sHL[0..2], cstate
    {
        float hc[12];
        #pragma unroll
        for (int i = 0; i < 12; i++) hc[i] = F[0][i];
        #pragma unroll
        for (int i = 0; i < 12; i++)
            sHL[(0 * 64 + h2) * 48 + ng * 12 + i] = __float2half(hc[i]);
        #pragma unroll
        for (int k = 1; k <= 2; k++){
            #pragma unroll
            for (int i = 0; i < 12; i++) hc[i] = fmaf(vK[k], hc[i], F[k][i]);
            #pragma unroll
            for (int i = 0; i < 12; i++)
                sHL[(k * 64 + h2) * 48 + ng * 12 + i] = __float2half(hc[i]);
        }
        __half* cp = cstate + ((size_t)((b * 256 + hq * 64 + h2) * NBAND + band)) * 48 + ng * 12;
        #pragma unroll
        for (int i = 0; i < 12; i++)
            cp[i] = __float2half(fmaf(vK[3], hc[i], F[3][i]));
    }
    __syncthreads();

    // ---- P3: cross-segment terms (coeff = w from P1) + y store
    {
        f16x8 cva = *(const f16x8*)&sBC[t * 32 + 16];
        f16x8 cvb = *(const f16x8*)&sBC[t * 32 + 24];
        float cf[16];
        #pragma unroll
        for (int n = 0; n < 16; n++) cf[n] = (n < 8) ? (float)cva[n] : (float)cvb[n - 8];
        int k = t >> 4;
        if (k > 0){
            #pragma unroll
            for (int hh = 0; hh < 16; hh++){
                int h = Hb + hh;
                const __half* hl = &sHL[((k - 1) * 64 + h) * 48];
                f16x8 hv0 = *(const f16x8*)&hl[0];
                f16x8 hv1 = *(const f16x8*)&hl[8];
                f16x8 hv2 = *(const f16x8*)&hl[16];
                f16x8 hv3 = *(const f16x8*)&hl[24];
                f16x8 hv4 = *(const f16x8*)&hl[32];
                f16x8 hv5 = *(const f16x8*)&hl[40];
                #define HV(i) ((i)<8?(float)hv0[(i)]:(i)<16?(float)hv1[(i)-8]:(i)<24?(float)hv2[(i)-16]:\
                               (i)<32?(float)hv3[(i)-24]:(i)<40?(float)hv4[(i)-32]:(float)hv5[(i)-40])
                float a0 = 0.f, a1 = 0.f, a2 = 0.f;
                #pragma unroll
                for (int n = 0; n < 16; n++){
                    a0 = fmaf(cf[n], HV(n * 3 + 0), a0);
                    a1 = fmaf(cf[n], HV(n * 3 + 1), a1);
                    a2 = fmaf(cf[n], HV(n * 3 + 2), a2);
                }
                #undef HV
                y0[hh] = fmaf(w[hh], a0, y0[hh]);
                y1[hh] = fmaf(w[hh], a1, y1[hh]);
                y2[hh] = fmaf(w[hh], a2, y2[hh]);
            }
        }
        __half* yp = y + (size_t)(b * LEN + row0 + t) * DINNER + hq * 192 + hsub * 48;
        #pragma unroll
        for (int c = 0; c < 6; c++){
            f16x8 pk;
            #pragma unroll
            for (int e2 = 0; e2 < 8; e2++){
                int gi = c * 8 + e2;
                int hh = gi / 3, p = gi % 3;
                pk[e2] = (_Float16)(p == 0 ? y0[hh] : (p == 1 ? y1[hh] : y2[hh]));
            }
            *(f16x8*)&yp[c * 8] = pk;
        }
    }
}

// ---------------------------------------------------------------------------
// scan pass B: per (b,h), combine band summaries sequentially; overwrite
// cstate[band] in place with the INITIAL state of that band.
// ---------------------------------------------------------------------------
__global__ __launch_bounds__(64) void k_scanB(__half* __restrict__ cstate,
                                              const float* __restrict__ dsum){
    int bh = blockIdx.x;               // 0..1023
    int lane = threadIdx.x;
    if (lane >= 48) return;
    __half* st = cstate + (size_t)bh * NBAND * 48 + lane;
    const float* dd = dsum + (size_t)bh * NBAND;
    float H = 0.f;
    for (int c = 0; c < NBAND; c++){
        float d = dd[c];
        float s = __half2float(st[(size_t)c * 48]);
        st[(size_t)c * 48] = __float2half(H);
        H = fmaf(H, d, s);
    }
}

// ---------------------------------------------------------------------------
// fused correction + gated RMSNorm:
//   y_full = y_scan + E0*(C . h_band_init) + D_skip*x
//   y_out  = (y_full * silu(z)) * rsqrt(mean(sq)+eps) * nw
// One block per row; h_init for the row's band staged in LDS (L2-hot).
// ---------------------------------------------------------------------------
__global__ __launch_bounds__(256) void k_norm(__half* __restrict__ y,
                                              const __half* __restrict__ z,
                                              const __half* __restrict__ xcc,
                                              const float* __restrict__ E0,
                                              const __half* __restrict__ cstate,
                                              const float* __restrict__ D_skip,
                                              const float* __restrict__ nw){
    __shared__ __align__(16) char nsm[24576 + 64];
    __half* sHI = (__half*)nsm;                 // [256][48]
    float*  sCf = (float*)(nsm + 24576);        // [16]
    __shared__ float wsum[4];
    int r = blockIdx.x;
    int b = r >> 11, l = r & (LEN - 1), band = l >> 6;
    int tid = threadIdx.x;
    int wv = tid >> 6, lane = tid & 63;

    #pragma unroll
    for (int i = 0; i < 6; i++){
        int chunk = (wv + i * 4) * 64 + lane;    // 0..1535
        int head = chunk / 6, off = chunk % 6;
        gl2lds16((const _Float16*)((const char*)cstate +
                   ((size_t)(b * 256 + head) * NBAND + band) * 96 + off * 16),
                 (_Float16*)(nsm + (wv + i * 4) * 1024));
    }
    if (tid < 16)
        sCf[tid] = __half2float(xcc[(size_t)r * CONVDIM + DINNER + DSTATE + tid]);
    __syncthreads();

    const __half* zr = z + (size_t)r * DINNER;
    const __half* xr = xcc + (size_t)r * CONVDIM;
    const float*  er = E0 + (size_t)r * 256;
    __half* yr = y + (size_t)r * DINNER;
    float tv[3];
    #pragma unroll
    for (int q = 0; q < 3; q++){
        int e = tid + q * 256;
        int h = e / 3, p = e - h * 3;
        float corr = 0.f;
        #pragma unroll
        for (int n = 0; n < 16; n++)
            corr = fmaf(sCf[n], __half2float(sHI[h * 48 + n * 3 + p]), corr);
        float yf = __half2float(yr[e]) + er[h] * corr + D_skip[h] * __half2float(xr[e]);
        tv[q] = yf * silu_(__half2float(zr[e]));
    }
    float ss = tv[0] * tv[0] + tv[1] * tv[1] + tv[2] * tv[2];
    #pragma unroll
    for (int m = 1; m < 64; m <<= 1) ss += __shfl_xor(ss, m, 64);
    if ((tid & 63) == 0) wsum[tid >> 6] = ss;
    __syncthreads();
    float tot = wsum[0] + wsum[1] + wsum[2] + wsum[3];
    float sc = rsqrtf(tot / (float)DINNER + EPS_);
    #pragma unroll
    for (int q = 0; q < 3; q++){
        int e = tid + q * 256;
        yr[e] = __float2half(tv[q] * sc * nw[e]);
    }
}

// ---------------------------------------------------------------------------
extern "C" void kernel_launch(void* const* d_in, const int* in_sizes, int n_in,
                              void* d_out, int out_size, void* d_ws, size_t ws_size,
                              hipStream_t stream) {
    const float* x          = (const float*)d_in[0];
    const float* proj_w     = (const float*)d_in[1];
    const float* in_proj_w  = (const float*)d_in[2];
    const float* conv_w     = (const float*)d_in[3];
    const float* conv_b     = (const float*)d_in[4];
    const float* dt_bias    = (const float*)d_in[5];
    const float* A_log      = (const float*)d_in[6];
    const float* D_skip     = (const float*)d_in[7];
    const float* norm_w     = (const float*)d_in[8];
    const float* out_proj_w = (const float*)d_in[9];
    float* out = (float*)d_out;

    // d_out (8 MB) triple-duty:
    //   1) fp16 proj/in_proj weights (dead after gemm<256,1>)
    //   2) E0 = exp(A*cum) fp32 [8192][256] (k_y..k_norm)
    //   3) final output (gemm<768,2> overwrites everything)
    char* ob = (char*)d_out;
    _Float16* pw_h  = (_Float16*)ob;                   //   262,144 B (256x512)
    _Float16* ipw_h = (_Float16*)(ob + 262144);        //   933,888 B (1824x256)
    float*    E0    = (float*)d_out;                   // 8,388,608 B exactly

    char* wsb = (char*)d_ws;
    _Float16* xcol  = (_Float16*)(wsb);                // 8192x512 fp16
    _Float16* u_h   = (_Float16*)(wsb + 8388608);      // 8192x256 fp16
    __half*   xcc_h = (__half*)(wsb);                  // 8192x800 fp16 (alias)
    __half*   z_h   = (__half*)(wsb + 13107200);       // 8192x768
    __half*   xbc_h = (__half*)(wsb + 25690112);       // 8192x800
    __half*   y_h   = xbc_h;                           // alias: xbc dead after dwconv
    __half*   dt_h  = (__half*)(wsb + 38797312);       // 8192x256
    __half*   cstate= (__half*)(wsb + 42991616);       // 1024*32*48 fp16 (3.1MB)
    float*    dsum  = (float*)(wsb + 46137344);        // 1024*32 f32
    _Float16* opw_h = (_Float16*)(wsb + 46268416);     // 256x768 fp16 -> total 46,661,632

    k_f2h3  <<<128, 256, 0, stream>>>(proj_w, pw_h, DMODEL * CIN * 4,
                                      in_proj_w, ipw_h, DINPROJ * DMODEL,
                                      out_proj_w, opw_h, DMODEL * DINNER);
    k_im2col<<<128, 256, 0, stream>>>(x, xcol);
    k_gemm<512, 0><<<dim3(64, 2), 256, 0, stream>>>(xcol, pw_h, nullptr,
        u_h, nullptr, nullptr, nullptr, nullptr);
    k_gemm<256, 1><<<dim3(64, 15), 256, 0, stream>>>(u_h, ipw_h, dt_bias,
        nullptr, (_Float16*)z_h, (_Float16*)xbc_h, (_Float16*)dt_h, nullptr);
    k_dwconv<<<25600, 256, 0, stream>>>(xbc_h, conv_w, conv_b, xcc_h);
    k_y     <<<dim3(NBAND, 4, B_), 256, 0, stream>>>(dt_h, xcc_h, A_log,
                                                     y_h, E0, cstate, dsum);
    k_scanB <<<1024, 64, 0, stream>>>(cstate, dsum);
    k_norm  <<<8192, 256, 0, stream>>>(y_h, z_h, xcc_h, E0, cstate,
                                       D_skip, norm_w);
    k_gemm<768, 2><<<dim3(64, 2), 256, 0, stream>>>((const _Float16*)y_h, opw_h,
        nullptr, nullptr, nullptr, nullptr, nullptr, out);
}

// Round 15
// 273.059 us; speedup vs baseline: 1.3094x; 1.0352x over previous
//
#include <hip/hip_runtime.h>
#include <hip/hip_fp16.h>
#include <math.h>

// Problem constants
#define B_     4
#define CIN    128
#define LEN    2048
#define DMODEL 256
#define DSTATE 16
#define NHEADS 256
#define DINNER 768
#define CONVDIM 800      // DINNER + 2*DSTATE
#define DINPROJ 1824     // 2*DINNER + 2*DSTATE + NHEADS
#define EPS_   1e-5f
#define BAND   64        // rows per k_y block
#define NBAND  32        // LEN / BAND

typedef _Float16 f16x8 __attribute__((ext_vector_type(8)));
typedef _Float16 f16x4 __attribute__((ext_vector_type(4)));
typedef float    f32x4 __attribute__((ext_vector_type(4)));

__device__ __forceinline__ float silu_(float x){ return x / (1.0f + __expf(-x)); }
__device__ __forceinline__ float softplus_(float x){
    return x > 0.f ? x + log1pf(__expf(-x)) : log1pf(__expf(x));
}

// async global->LDS, 16B per lane; LDS dest = wave-uniform base + lane*16
__device__ __forceinline__ void gl2lds16(const _Float16* g, _Float16* l){
    __builtin_amdgcn_global_load_lds(
        (const __attribute__((address_space(1))) void*)g,
        (__attribute__((address_space(3))) void*)l, 16, 0, 0);
}

// ---------------------------------------------------------------------------
// fp32 -> fp16 convert for the three weight tensors, one launch
// ---------------------------------------------------------------------------
__global__ __launch_bounds__(256) void k_f2h3(const float* __restrict__ a0,
                                              _Float16* __restrict__ o0, int n0,
                                              const float* __restrict__ a1,
                                              _Float16* __restrict__ o1, int n1,
                                              const float* __restrict__ a2,
                                              _Float16* __restrict__ o2, int n2){
    int stride = gridDim.x * 256;
    for (int i = blockIdx.x * 256 + threadIdx.x; i < n0; i += stride)
        o0[i] = (_Float16)a0[i];
    for (int i = blockIdx.x * 256 + threadIdx.x; i < n1; i += stride)
        o1[i] = (_Float16)a1[i];
    for (int i = blockIdx.x * 256 + threadIdx.x; i < n2; i += stride)
        o2[i] = (_Float16)a2[i];
}

// ---------------------------------------------------------------------------
// im2col for the conv projection: xcol[(b,l)][(ci,k)] = x[b,ci,l-1+k], fp16.
// ---------------------------------------------------------------------------
__global__ __launch_bounds__(256) void k_im2col(const float* __restrict__ x,
                                                _Float16* __restrict__ xcol){
    __shared__ float xs[CIN][68];      // 67 used
    int blk = blockIdx.x;              // 0..127
    int b  = blk >> 5;
    int l0 = (blk & 31) << 6;          // *64
    const float* xb = x + (size_t)b * CIN * LEN;
    for (int idx = threadIdx.x; idx < CIN * 67; idx += 256){
        int ci = idx / 67, j = idx % 67;
        int gl = l0 - 1 + j;
        xs[ci][j] = (gl >= 0 && gl < LEN) ? xb[ci * LEN + gl] : 0.f;
    }
    __syncthreads();
    #pragma unroll
    for (int v = 0; v < 16; v++){
        int id = v * 256 + threadIdx.x;   // 0..4095
        int rl = id >> 6, c = id & 63;    // row-in-tile, 16B chunk
        f16x8 pk;
        #pragma unroll
        for (int e = 0; e < 8; e++){
            int ci = c * 2 + (e >> 2), k = e & 3;
            pk[e] = (_Float16)xs[ci][rl + k];
        }
        *(f16x8*)&xcol[((size_t)(b * LEN + l0 + rl)) * 512 + c * 8] = pk;
    }
}

// ---------------------------------------------------------------------------
// Shared MFMA GEMM: C[M][N] = A[M][K] . Bw[N][K]^T, f16 inputs, fp32 acc.
// BK=64 (half the barrier drains of BK=32); LDS rows are 128B so fragment
// reads XOR-swizzle the chunk index (rule: linear gl2lds dest + inverse-
// swizzled global source + same swizzle on read). Epilogues stage the tile
// through LDS (EP aliases As/Bs, dead after the K loop) -> 16B coalesced
// global stores only.
// ---------------------------------------------------------------------------
template<int K, int EPI>
__global__ __launch_bounds__(256) void k_gemm(const _Float16* __restrict__ A,
                                              const _Float16* __restrict__ Bw,
                                              const float* __restrict__ dt_bias,
                                              _Float16* __restrict__ o_u,
                                              _Float16* __restrict__ o_z,
                                              _Float16* __restrict__ o_xbc,
                                              _Float16* __restrict__ o_dt,
                                              float* __restrict__ o_f){
    __shared__ __align__(16) char smem[32768];
    _Float16* As = (_Float16*)smem;            // [128][64] halves, linear
    _Float16* Bs = (_Float16*)(smem + 16384);  // [128][64] halves, linear
    char* EP = smem;                           // epilogue staging (alias)
    int tid  = threadIdx.x;
    int wv   = tid >> 6;
    int lane = tid & 63;
    int quad = lane >> 4;
    int l16  = lane & 15;
    int m0 = blockIdx.x * 128;
    int n0 = blockIdx.y * 128;
    int wm = (wv >> 1) * 64;
    int wn = (wv & 1) * 64;

    f32x4 acc[4][4];
    #pragma unroll
    for (int i = 0; i < 4; i++)
        #pragma unroll
        for (int j = 0; j < 4; j++)
            acc[i][j] = (f32x4){0.f, 0.f, 0.f, 0.f};

    for (int k0 = 0; k0 < K; k0 += 64){
        // stage: 4 instructions per wave per matrix; lane covers row
        // rbase+(lane>>3), physical chunk lane&7 <- global chunk xor'd
        #pragma unroll
        for (int j = 0; j < 4; j++){
            int rbase = wv * 32 + j * 8;
            int rrow  = rbase + (lane >> 3);
            int cgl   = (lane & 7) ^ (lane >> 3);   // global chunk (swizzled)
            int ar = m0 + rrow;
            gl2lds16(A + (size_t)ar * K + k0 + cgl * 8, &As[rbase * 64]);
            int nr = n0 + rrow;
            if (EPI == 1) nr = nr > (DINPROJ - 1) ? (DINPROJ - 1) : nr;
            gl2lds16(Bw + (size_t)nr * K + k0 + cgl * 8, &Bs[rbase * 64]);
        }
        __syncthreads();               // vmcnt(0) drain before barrier
        #pragma unroll
        for (int kk = 0; kk < 2; kk++){
            f16x8 af[4], bf[4];
            int sw = (l16 & 7);
            #pragma unroll
            for (int i = 0; i < 4; i++)
                af[i] = *(const f16x8*)&As[(wm + i * 16 + l16) * 64 +
                                           (((kk * 4 + quad) ^ sw) * 8)];
            #pragma unroll
            for (int j = 0; j < 4; j++)
                bf[j] = *(const f16x8*)&Bs[(wn + j * 16 + l16) * 64 +
                                           (((kk * 4 + quad) ^ sw) * 8)];
            #pragma unroll
            for (int i = 0; i < 4; i++)
                #pragma unroll
                for (int j = 0; j < 4; j++)
                    acc[i][j] = __builtin_amdgcn_mfma_f32_16x16x32_f16(
                                    af[i], bf[j], acc[i][j], 0, 0, 0);
        }
        __syncthreads();
    }

    if (EPI == 0 || EPI == 1){
        // two phases; each stages rows {p*32..p*32+31} of both 64-row halves
        // as fp16 [2][32][136] then streams f16x8 coalesced stores.
        _Float16* T = (_Float16*)EP;
        #pragma unroll
        for (int p = 0; p < 2; p++){
            if (p) __syncthreads();
            {
                _Float16* Th = T + (wv >> 1) * (32 * 136);
                #pragma unroll
                for (int ii = 0; ii < 2; ii++){
                    int i = 2 * p + ii;
                    int r32 = i * 16 + quad * 4 - p * 32;   // 0..28
                    #pragma unroll
                    for (int j = 0; j < 4; j++){
                        int col = wn + j * 16 + l16;
                        #pragma unroll
                        for (int r = 0; r < 4; r++)
                            Th[(r32 + r) * 136 + col] = (_Float16)acc[i][j][r];
                    }
                }
            }
            __syncthreads();
            #pragma unroll
            for (int u = 0; u < 4; u++){
                int id = u * 256 + tid;            // 0..1023
                int hb = id >> 9, rem = id & 511;
                int r32 = rem >> 4, cc = rem & 15;
                int grow = m0 + hb * 64 + p * 32 + r32;
                int abscol = n0 + cc * 8;
                f16x8 v = *(const f16x8*)&T[hb * (32 * 136) + r32 * 136 + cc * 8];
                if (EPI == 0){
                    *(f16x8*)&o_u[(size_t)grow * DMODEL + abscol] = v;
                } else {
                    if (abscol < DINNER){
                        *(f16x8*)&o_z[(size_t)grow * DINNER + abscol] = v;
                    } else if (abscol < DINNER + CONVDIM){
                        *(f16x8*)&o_xbc[(size_t)grow * CONVDIM + (abscol - DINNER)] = v;
                    } else if (abscol < DINPROJ){
                        int hh = abscol - (DINNER + CONVDIM);
                        f16x8 o;
                        #pragma unroll
                        for (int e = 0; e < 8; e++)
                            o[e] = (_Float16)softplus_((float)v[e] + dt_bias[hh + e]);
                        *(f16x8*)&o_dt[(size_t)grow * NHEADS + hh] = o;
                    }
                }
            }
        }
    } else {
        // transposed fp32 out: 4 quarters of 32 rows, col-major [128][36] f32;
        // acc f32x4 = 4 consecutive rows -> single ds_write_b128; reads are
        // 128B-per-column coalesced f32x4 runs.
        float* Tf = (float*)EP;
        int bb = m0 >> 11, ll0 = m0 & (LEN - 1);
        #pragma unroll
        for (int q = 0; q < 4; q++){
            if (q) __syncthreads();
            if ((wv >> 1) == (q >> 1)){
                #pragma unroll
                for (int ii = 0; ii < 2; ii++){
                    int i = (q & 1) * 2 + ii;
                    int r32 = i * 16 + quad * 4 - (q & 1) * 32;  // 0..28
                    #pragma unroll
                    for (int j = 0; j < 4; j++){
                        int col = wn + j * 16 + l16;
                        *(f32x4*)&Tf[col * 36 + r32] = acc[i][j];
                    }
                }
            }
            __syncthreads();
            #pragma unroll
            for (int u = 0; u < 4; u++){
                int id = u * 256 + tid;            // 0..1023
                int col = id >> 3, seg = id & 7;
                f32x4 v = *(const f32x4*)&Tf[col * 36 + seg * 4];
                *(f32x4*)&o_f[(((size_t)(bb * DMODEL + n0 + col)) << 11)
                              + ll0 + q * 32 + seg * 4] = v;
            }
        }
    }
}

// ---------------------------------------------------------------------------
// depthwise causal conv (4-tap) + bias + SiLU, register-window row-marching:
// each thread owns 8 channels and marches 8 consecutive rows, loading the
// 11-row window once (11 loads + 8 stores per 64 outputs vs 48 VMEM in the
// scalar form; each tap value loaded exactly once).
// ---------------------------------------------------------------------------
__global__ __launch_bounds__(256) void k_dwconv(const __half* __restrict__ xbc,
                                                const float* __restrict__ cw,
                                                const float* __restrict__ cb,
                                                __half* __restrict__ xcc){
    int g = blockIdx.x * 256 + threadIdx.x;   // < 102400
    int chunk = g % 100;
    int seg   = g / 100;                      // 0..1023
    int b  = seg >> 8;
    int l0 = (seg & 255) << 3;                // row base within batch
    int c0 = chunk * 8;

    float4 wv[8];
    float  bias[8];
    #pragma unroll
    for (int e = 0; e < 8; e++){
        wv[e]   = *(const float4*)(cw + (c0 + e) * 4);
        bias[e] = cb[c0 + e];
    }

    const char* base = (const char*)xbc +
        ((size_t)(b * LEN + l0) * CONVDIM + c0) * 2;
    f16x8 v[11];
    #pragma unroll
    for (int i = 0; i < 11; i++){
        int l = l0 - 3 + i;
        if (l >= 0)
            v[i] = *(const f16x8*)(base + (ptrdiff_t)(i - 3) * (CONVDIM * 2));
        else {
            f16x8 z;
            #pragma unroll
            for (int e = 0; e < 8; e++) z[e] = (_Float16)0.f;
            v[i] = z;
        }
    }

    char* ob = (char*)xcc + ((size_t)(b * LEN + l0) * CONVDIM + c0) * 2;
    #pragma unroll
    for (int j = 0; j < 8; j++){
        f16x8 o;
        #pragma unroll
        for (int e = 0; e < 8; e++){
            float a = bias[e];
            a = fmaf((float)v[j][e],     wv[e].x, a);
            a = fmaf((float)v[j + 1][e], wv[e].y, a);
            a = fmaf((float)v[j + 2][e], wv[e].z, a);
            a = fmaf((float)v[j + 3][e], wv[e].w, a);
            o[e] = (_Float16)silu_(a);
        }
        *(f16x8*)(ob + (ptrdiff_t)j * (CONVDIM * 2)) = o;
    }
}

// ---------------------------------------------------------------------------
// k_y: chunked-SSD scan. One block per (band of 64 rows, head-quarter, b).
// ROUND-5 EXACT (56.7us measured; FETCH 8.7MB / WRITE 24.6MB): round-2
// memory structure + exp-free telescoping-product arithmetic.
// ---------------------------------------------------------------------------
__global__ __launch_bounds__(256) void k_y(const __half* __restrict__ dtb,
                                           const __half* __restrict__ xcc,
                                           const float* __restrict__ A_log,
                                           __half* __restrict__ y,
                                           float* __restrict__ E0,
                                           __half* __restrict__ cstate,
                                           float* __restrict__ dsum){
    // LDS layout (bytes):
    //   [0,4096)      sBC  [64][32]h   (B0..15 | C0..15, gl2lds linear)
    //   [4096,28672)  sX   [64][192]h  (x, premultiplied by dt after P0.5)
    //                 sHL  [3][64][48]h ALIAS over sX (written after P2)
    //   [28672,36864) sDT  [64][64]h   (raw dt, gl2lds linear)
    //   [36864,54272) sD   [64][68]f   step decay D[t][h] = exp(A_h*dt)
    //   [54272,59392) sG   [64][20]f   G[t][ss], ss = s within 16-segment
    __shared__ __align__(16) char smem[59392];
    __half* sBC = (__half*)smem;
    __half* sX  = (__half*)(smem + 4096);
    __half* sHL = (__half*)(smem + 4096);
    __half* sDT = (__half*)(smem + 28672);
    float*  sD  = (float*)(smem + 36864);
    float*  sG  = (float*)(smem + 54272);

    int band = blockIdx.x, hq = blockIdx.y, b = blockIdx.z;
    int row0 = band * BAND;
    int tid = threadIdx.x;
    int wv = tid >> 6, lane = tid & 63;

    // ---- P0: stage BC (4), X (24), DT (8) via gl2lds16, linear LDS
    {
        int c = wv, slot = c * 64 + lane;
        int row = slot >> 2, off = slot & 3;
        gl2lds16((const _Float16*)((const char*)xcc +
                   (size_t)(b * LEN + row0 + row) * 1600 + 1536 + off * 16),
                 (_Float16*)(smem + c * 1024));
    }
    #pragma unroll
    for (int i = 0; i < 6; i++){
        int c = wv + i * 4, slot = c * 64 + lane;
        int row = slot / 24, off = slot % 24;
        gl2lds16((const _Float16*)((const char*)xcc +
                   (size_t)(b * LEN + row0 + row) * 1600 + hq * 384 + off * 16),
                 (_Float16*)(smem + 4096 + c * 1024));
    }
    #pragma unroll
    for (int i = 0; i < 2; i++){
        int c = wv + i * 4, slot = c * 64 + lane;
        int row = slot >> 3, off = slot & 7;
        gl2lds16((const _Float16*)((const char*)dtb +
                   (size_t)(b * LEN + row0 + row) * 512 + hq * 128 + off * 16),
                 (_Float16*)(smem + 28672 + c * 1024));
    }
    __syncthreads();

    // ---- P0.5a: step decays D[t][h] = exp(A_h * dt[t][h])
    {
        int h = tid & 63, tb = tid >> 6;
        float A = -__expf(A_log[hq * 64 + h]);
        #pragma unroll
        for (int i = 0; i < 16; i++){
            int t = tb + i * 4;
            sD[t * 68 + h] = __expf(A * __half2float(sDT[t * 64 + h]));
        }
    }
    __syncthreads();

    // ---- P0.5b: E0 prefix-product (0..63) | G dots (64..127) | x*=dt (128..255)
    if (tid < 64){
        int h = tid;
        float E = 1.f;
        float* ep = E0 + ((size_t)(b * LEN + row0)) * 256 + hq * 64 + h;
        for (int t = 0; t < 64; t++){
            E *= sD[t * 68 + h];
            *ep = E;
            ep += 256;
        }
        dsum[(size_t)(b * 256 + hq * 64 + h) * NBAND + band] = E;
    } else if (tid < 128){
        int tt = tid - 64;                       // one t row: 16 dots
        f16x8 ca = *(const f16x8*)&sBC[tt * 32 + 16];
        f16x8 cb = *(const f16x8*)&sBC[tt * 32 + 24];
        float cf[16];
        #pragma unroll
        for (int n = 0; n < 16; n++) cf[n] = (n < 8) ? (float)ca[n] : (float)cb[n - 8];
        for (int ss = 0; ss < 16; ss++){
            int s = (tt & 48) + ss;
            f16x8 ba = *(const f16x8*)&sBC[s * 32];
            f16x8 bb = *(const f16x8*)&sBC[s * 32 + 8];
            float acc = 0.f;
            #pragma unroll
            for (int n = 0; n < 8; n++)
                acc += cf[n] * (float)ba[n] + cf[n + 8] * (float)bb[n];
            sG[tt * 20 + ss] = acc;
        }
    } else {
        for (int idx = tid - 128; idx < 4096; idx += 128){
            int t = idx >> 6, h = idx & 63;
            float dtv = __half2float(sDT[t * 64 + h]);
            int xi = t * 192 + h * 3;
            sX[xi]     = __float2half(__half2float(sX[xi])     * dtv);
            sX[xi + 1] = __float2half(__half2float(sX[xi + 1]) * dtv);
            sX[xi + 2] = __float2half(__half2float(sX[xi + 2]) * dtv);
        }
    }
    __syncthreads();

    // ---- P1: within-segment masked pair sum via running decay products
    int t = tid >> 2, hsub = tid & 3, Hb = hsub * 16;
    int tmod = t & 15;
    float w[16], y0[16], y1[16], y2[16];
    #pragma unroll
    for (int i = 0; i < 16; i++){ w[i] = 1.f; y0[i] = 0.f; y1[i] = 0.f; y2[i] = 0.f; }

    for (int d = 0; d <= tmod; d++){
        int s = t - d;
        float g = sG[t * 20 + (tmod - d)];
        f32x4 Dv[4];
        #pragma unroll
        for (int k4 = 0; k4 < 4; k4++)
            Dv[k4] = *(const f32x4*)&sD[s * 68 + Hb + k4 * 4];
        f16x8 xv0 = *(const f16x8*)&sX[s * 192 + Hb * 3];
        f16x8 xv1 = *(const f16x8*)&sX[s * 192 + Hb * 3 + 8];
        f16x8 xv2 = *(const f16x8*)&sX[s * 192 + Hb * 3 + 16];
        f16x8 xv3 = *(const f16x8*)&sX[s * 192 + Hb * 3 + 24];
        f16x8 xv4 = *(const f16x8*)&sX[s * 192 + Hb * 3 + 32];
        f16x8 xv5 = *(const f16x8*)&sX[s * 192 + Hb * 3 + 40];
        #define XV(i) ((i)<8?(float)xv0[(i)]:(i)<16?(float)xv1[(i)-8]:(i)<24?(float)xv2[(i)-16]:\
                       (i)<32?(float)xv3[(i)-24]:(i)<40?(float)xv4[(i)-32]:(float)xv5[(i)-40])
        #pragma unroll
        for (int hh = 0; hh < 16; hh++){
            float wg = w[hh] * g;
            y0[hh] = fmaf(wg, XV(hh * 3 + 0), y0[hh]);
            y1[hh] = fmaf(wg, XV(hh * 3 + 1), y1[hh]);
            y2[hh] = fmaf(wg, XV(hh * 3 + 2), y2[hh]);
            w[hh] *= Dv[hh >> 2][hh & 3];
        }
        #undef XV
    }
    // after loop: w[hh] = exp(a_t - a_{tseg-1})  (used in P3)

    // ---- P2: segment-final states (reads only), all 256 threads
    int h2 = tid >> 2, ng = tid & 3;
    float F[4][12];
    float vK[4];
    #pragma unroll
    for (int k = 0; k < 4; k++){
        #pragma unroll
        for (int i = 0; i < 12; i++) F[k][i] = 0.f;
        float v = 1.f;
        for (int ss = 15; ss >= 0; ss--){
            int s = k * 16 + ss;
            float x0 = __half2float(sX[s * 192 + h2 * 3]);
            float x1 = __half2float(sX[s * 192 + h2 * 3 + 1]);
            float x2 = __half2float(sX[s * 192 + h2 * 3 + 2]);
            f16x4 bv = *(const f16x4*)&sBC[s * 32 + ng * 4];
            #pragma unroll
            for (int nn = 0; nn < 4; nn++){
                float wb = v * (float)bv[nn];
                F[k][nn * 3 + 0] = fmaf(wb, x0, F[k][nn * 3 + 0]);
                F[k][nn * 3 + 1] = fmaf(wb, x1, F[k][nn * 3 + 1]);
                F[k][nn * 3 + 2] = fmaf(wb, x2, F[k][nn * 3 + 2]);
            }
            v *= sD[s * 68 + h2];
        }
        vK[k] = v;                     // segment decay
    }

    __syncthreads();   // all LDS reads of sX done before sHL overwrite

    // ---- P2b: chain boundary states; write sHL[0..2], cstate
    {
        float hc[12];
        #pragma unroll
        for (int i = 0; i < 12; i++) hc[i] = F[0][i];
        #pragma unroll
        for (int i = 0; i < 12; i++)
            sHL[(0 * 64 + h2) * 48 + ng * 12 + i] = __float2half(hc[i]);
        #pragma unroll
        for (int k = 1; k <= 2; k++){
            #pragma unroll
            for (int i = 0; i < 12; i++) hc[i] = fmaf(vK[k], hc[i], F[k][i]);
            #pragma unroll
            for (int i = 0; i < 12; i++)
                sHL[(k * 64 + h2) * 48 + ng * 12 + i] = __float2half(hc[i]);
        }
        __half* cp = cstate + ((size_t)((b * 256 + hq * 64 + h2) * NBAND + band)) * 48 + ng * 12;
        #pragma unroll
        for (int i = 0; i < 12; i++)
            cp[i] = __float2half(fmaf(vK[3], hc[i], F[3][i]));
    }
    __syncthreads();

    // ---- P3: cross-segment terms (coeff = w from P1) + y store
    {
        f16x8 cva = *(const f16x8*)&sBC[t * 32 + 16];
        f16x8 cvb = *(const f16x8*)&sBC[t * 32 + 24];
        float cf[16];
        #pragma unroll
        for (int n = 0; n < 16; n++) cf[n] = (n < 8) ? (float)cva[n] : (float)cvb[n - 8];
        int k = t >> 4;
        if (k > 0){
            #pragma unroll
            for (int hh = 0; hh < 16; hh++){
                int h = Hb + hh;
                const __half* hl = &sHL[((k - 1) * 64 + h) * 48];
                f16x8 hv0 = *(const f16x8*)&hl[0];
                f16x8 hv1 = *(const f16x8*)&hl[8];
                f16x8 hv2 = *(const f16x8*)&hl[16];
                f16x8 hv3 = *(const f16x8*)&hl[24];
                f16x8 hv4 = *(const f16x8*)&hl[32];
                f16x8 hv5 = *(const f16x8*)&hl[40];
                #define HV(i) ((i)<8?(float)hv0[(i)]:(i)<16?(float)hv1[(i)-8]:(i)<24?(float)hv2[(i)-16]:\
                               (i)<32?(float)hv3[(i)-24]:(i)<40?(float)hv4[(i)-32]:(float)hv5[(i)-40])
                float a0 = 0.f, a1 = 0.f, a2 = 0.f;
                #pragma unroll
                for (int n = 0; n < 16; n++){
                    a0 = fmaf(cf[n], HV(n * 3 + 0), a0);
                    a1 = fmaf(cf[n], HV(n * 3 + 1), a1);
                    a2 = fmaf(cf[n], HV(n * 3 + 2), a2);
                }
                #undef HV
                y0[hh] = fmaf(w[hh], a0, y0[hh]);
                y1[hh] = fmaf(w[hh], a1, y1[hh]);
                y2[hh] = fmaf(w[hh], a2, y2[hh]);
            }
        }
        __half* yp = y + (size_t)(b * LEN + row0 + t) * DINNER + hq * 192 + hsub * 48;
        #pragma unroll
        for (int c = 0; c < 6; c++){
            f16x8 pk;
            #pragma unroll
            for (int e2 = 0; e2 < 8; e2++){
                int gi = c * 8 + e2;
                int hh = gi / 3, p = gi % 3;
                pk[e2] = (_Float16)(p == 0 ? y0[hh] : (p == 1 ? y1[hh] : y2[hh]));
            }
            *(f16x8*)&yp[c * 8] = pk;
        }
    }
}

// ---------------------------------------------------------------------------
// scan pass B: per (b,h), combine band summaries sequentially; overwrite
// cstate[band] in place with the INITIAL state of that band.
// ---------------------------------------------------------------------------
__global__ __launch_bounds__(64) void k_scanB(__half* __restrict__ cstate,
                                              const float* __restrict__ dsum){
    int bh = blockIdx.x;               // 0..1023
    int lane = threadIdx.x;
    if (lane >= 48) return;
    __half* st = cstate + (size_t)bh * NBAND * 48 + lane;
    const float* dd = dsum + (size_t)bh * NBAND;
    float H = 0.f;
    for (int c = 0; c < NBAND; c++){
        float d = dd[c];
        float s = __half2float(st[(size_t)c * 48]);
        st[(size_t)c * 48] = __float2half(H);
        H = fmaf(H, d, s);
    }
}

// ---------------------------------------------------------------------------
// fused correction + gated RMSNorm:
//   y_full = y_scan + E0*(C . h_band_init) + D_skip*x
//   y_out  = (y_full * silu(z)) * rsqrt(mean(sq)+eps) * nw
// One block per row; h_init for the row's band staged in LDS (L2-hot).
// ---------------------------------------------------------------------------
__global__ __launch_bounds__(256) void k_norm(__half* __restrict__ y,
                                              const __half* __restrict__ z,
                                              const __half* __restrict__ xcc,
                                              const float* __restrict__ E0,
                                              const __half* __restrict__ cstate,
                                              const float* __restrict__ D_skip,
                                              const float* __restrict__ nw){
    __shared__ __align__(16) char nsm[24576 + 64];
    __half* sHI = (__half*)nsm;                 // [256][48]
    float*  sCf = (float*)(nsm + 24576);        // [16]
    __shared__ float wsum[4];
    int r = blockIdx.x;
    int b = r >> 11, l = r & (LEN - 1), band = l >> 6;
    int tid = threadIdx.x;
    int wv = tid >> 6, lane = tid & 63;

    #pragma unroll
    for (int i = 0; i < 6; i++){
        int chunk = (wv + i * 4) * 64 + lane;    // 0..1535
        int head = chunk / 6, off = chunk % 6;
        gl2lds16((const _Float16*)((const char*)cstate +
                   ((size_t)(b * 256 + head) * NBAND + band) * 96 + off * 16),
                 (_Float16*)(nsm + (wv + i * 4) * 1024));
    }
    if (tid < 16)
        sCf[tid] = __half2float(xcc[(size_t)r * CONVDIM + DINNER + DSTATE + tid]);
    __syncthreads();

    const __half* zr = z + (size_t)r * DINNER;
    const __half* xr = xcc + (size_t)r * CONVDIM;
    const float*  er = E0 + (size_t)r * 256;
    __half* yr = y + (size_t)r * DINNER;
    float tv[3];
    #pragma unroll
    for (int q = 0; q < 3; q++){
        int e = tid + q * 256;
        int h = e / 3, p = e - h * 3;
        float corr = 0.f;
        #pragma unroll
        for (int n = 0; n < 16; n++)
            corr = fmaf(sCf[n], __half2float(sHI[h * 48 + n * 3 + p]), corr);
        float yf = __half2float(yr[e]) + er[h] * corr + D_skip[h] * __half2float(xr[e]);
        tv[q] = yf * silu_(__half2float(zr[e]));
    }
    float ss = tv[0] * tv[0] + tv[1] * tv[1] + tv[2] * tv[2];
    #pragma unroll
    for (int m = 1; m < 64; m <<= 1) ss += __shfl_xor(ss, m, 64);
    if ((tid & 63) == 0) wsum[tid >> 6] = ss;
    __syncthreads();
    float tot = wsum[0] + wsum[1] + wsum[2] + wsum[3];
    float sc = rsqrtf(tot / (float)DINNER + EPS_);
    #pragma unroll
    for (int q = 0; q < 3; q++){
        int e = tid + q * 256;
        yr[e] = __float2half(tv[q] * sc * nw[e]);
    }
}

// ---------------------------------------------------------------------------
extern "C" void kernel_launch(void* const* d_in, const int* in_sizes, int n_in,
                              void* d_out, int out_size, void* d_ws, size_t ws_size,
                              hipStream_t stream) {
    const float* x          = (const float*)d_in[0];
    const float* proj_w     = (const float*)d_in[1];
    const float* in_proj_w  = (const float*)d_in[2];
    const float* conv_w     = (const float*)d_in[3];
    const float* conv_b     = (const float*)d_in[4];
    const float* dt_bias    = (const float*)d_in[5];
    const float* A_log      = (const float*)d_in[6];
    const float* D_skip     = (const float*)d_in[7];
    const float* norm_w     = (const float*)d_in[8];
    const float* out_proj_w = (const float*)d_in[9];
    float* out = (float*)d_out;

    // d_out (8 MB) triple-duty:
    //   1) fp16 proj/in_proj weights (dead after gemm<256,1>)
    //   2) E0 = exp(A*cum) fp32 [8192][256] (k_y..k_norm)
    //   3) final output (gemm<768,2> overwrites everything)
    char* ob = (char*)d_out;
    _Float16* pw_h  = (_Float16*)ob;                   //   262,144 B (256x512)
    _Float16* ipw_h = (_Float16*)(ob + 262144);        //   933,888 B (1824x256)
    float*    E0    = (float*)d_out;                   // 8,388,608 B exactly

    char* wsb = (char*)d_ws;
    _Float16* xcol  = (_Float16*)(wsb);                // 8192x512 fp16
    _Float16* u_h   = (_Float16*)(wsb + 8388608);      // 8192x256 fp16
    __half*   xcc_h = (__half*)(wsb);                  // 8192x800 fp16 (alias)
    __half*   z_h   = (__half*)(wsb + 13107200);       // 8192x768
    __half*   xbc_h = (__half*)(wsb + 25690112);       // 8192x800
    __half*   y_h   = xbc_h;                           // alias: xbc dead after dwconv
    __half*   dt_h  = (__half*)(wsb + 38797312);       // 8192x256
    __half*   cstate= (__half*)(wsb + 42991616);       // 1024*32*48 fp16 (3.1MB)
    float*    dsum  = (float*)(wsb + 46137344);        // 1024*32 f32
    _Float16* opw_h = (_Float16*)(wsb + 46268416);     // 256x768 fp16 -> total 46,661,632

    k_f2h3  <<<128, 256, 0, stream>>>(proj_w, pw_h, DMODEL * CIN * 4,
                                      in_proj_w, ipw_h, DINPROJ * DMODEL,
                                      out_proj_w, opw_h, DMODEL * DINNER);
    k_im2col<<<128, 256, 0, stream>>>(x, xcol);
    k_gemm<512, 0><<<dim3(64, 2), 256, 0, stream>>>(xcol, pw_h, nullptr,
        u_h, nullptr, nullptr, nullptr, nullptr);
    k_gemm<256, 1><<<dim3(64, 15), 256, 0, stream>>>(u_h, ipw_h, dt_bias,
        nullptr, (_Float16*)z_h, (_Float16*)xbc_h, (_Float16*)dt_h, nullptr);
    k_dwconv<<<400, 256, 0, stream>>>(xbc_h, conv_w, conv_b, xcc_h);
    k_y     <<<dim3(NBAND, 4, B_), 256, 0, stream>>>(dt_h, xcc_h, A_log,
                                                     y_h, E0, cstate, dsum);
    k_scanB <<<1024, 64, 0, stream>>>(cstate, dsum);
    k_norm  <<<8192, 256, 0, stream>>>(y_h, z_h, xcc_h, E0, cstate,
                                       D_skip, norm_w);
    k_gemm<768, 2><<<dim3(64, 2), 256, 0, stream>>>((const _Float16*)y_h, opw_h,
        nullptr, nullptr, nullptr, nullptr, nullptr, out);
}